// Round 1
// baseline (288.980 us; speedup 1.0000x reference)
//
#include <hip/hip_runtime.h>
#include <hip/hip_bf16.h>

// Problem constants
static constexpr int Bc   = 16;
static constexpr int Nc   = 256;
static constexpr int INDIM= 768;
static constexpr int MEMc = 300;
static constexpr int HIDc = 64;
static constexpr float NEGc   = -1e30f;
static constexpr float SLOPEc = 0.01f;

__device__ __forceinline__ float wredMax(float v) {
#pragma unroll
    for (int o = 32; o; o >>= 1) v = fmaxf(v, __shfl_xor(v, o, 64));
    return v;
}
__device__ __forceinline__ float wredSum(float v) {
#pragma unroll
    for (int o = 32; o; o >>= 1) v += __shfl_xor(v, o, 64);
    return v;
}

// ---------------------------------------------------------------------------
// K1: out[R x M] = X[R x K] @ W[K x M] + bias[M]   (fp32, 64x64 tile, 4x4/thread)
// ---------------------------------------------------------------------------
__global__ void __launch_bounds__(256) gemm_bias_kernel(
    const float* __restrict__ X, const float* __restrict__ W,
    const float* __restrict__ bias, float* __restrict__ out,
    int R, int K, int M) {
    __shared__ float As[16][68];  // [k][m], row stride 272B (16B aligned, bank-skewed)
    __shared__ float Bs[16][68];  // [k][n]
    int tid = threadIdx.x;
    int tx = tid & 15, ty = tid >> 4;
    int row0 = blockIdx.y * 64, col0 = blockIdx.x * 64;
    float acc[4][4] = {};

    for (int k0 = 0; k0 < K; k0 += 16) {
        // stage A tile: 64 rows x 16 k
        {
            int m = tid >> 2, kk = (tid & 3) * 4;
            int gr = row0 + m, gk = k0 + kk;
            float4 v = make_float4(0.f, 0.f, 0.f, 0.f);
            if (gr < R) {
                if (gk + 3 < K) {
                    v = *(const float4*)(X + (size_t)gr * K + gk);
                } else {
                    float* vv = (float*)&v;
                    for (int t = 0; t < 4; t++)
                        if (gk + t < K) vv[t] = X[(size_t)gr * K + gk + t];
                }
            }
            As[kk + 0][m] = v.x; As[kk + 1][m] = v.y;
            As[kk + 2][m] = v.z; As[kk + 3][m] = v.w;
        }
        // stage B tile: 16 k x 64 n
        {
            int kk = tid >> 4, n = (tid & 15) * 4;
            int gk = k0 + kk, gn = col0 + n;
            float4 v = make_float4(0.f, 0.f, 0.f, 0.f);
            if (gk < K) {
                if (gn + 3 < M) {
                    v = *(const float4*)(W + (size_t)gk * M + gn);
                } else {
                    float* vv = (float*)&v;
                    for (int t = 0; t < 4; t++)
                        if (gn + t < M) vv[t] = W[(size_t)gk * M + gn + t];
                }
            }
            *(float4*)&Bs[kk][n] = v;
        }
        __syncthreads();
#pragma unroll
        for (int kk = 0; kk < 16; kk++) {
            float a[4], b[4];
            *(float4*)a = *(const float4*)&As[kk][ty * 4];
            *(float4*)b = *(const float4*)&Bs[kk][tx * 4];
#pragma unroll
            for (int i = 0; i < 4; i++)
#pragma unroll
                for (int j = 0; j < 4; j++) acc[i][j] += a[i] * b[j];
        }
        __syncthreads();
    }
#pragma unroll
    for (int i = 0; i < 4; i++) {
        int gr = row0 + ty * 4 + i;
        if (gr >= R) continue;
#pragma unroll
        for (int j = 0; j < 4; j++) {
            int gc = col0 + tx * 4 + j;
            if (gc < M) out[(size_t)gr * M + gc] = acc[i][j] + bias[gc];
        }
    }
}

// ---------------------------------------------------------------------------
// K2: Si = H @ Wa ; Sj = H @ Wb + ab1   (H: R x 300, A1: 600 x 64)
// one block = 16 rows
// ---------------------------------------------------------------------------
__global__ void __launch_bounds__(256) attproj_kernel(
    const float* __restrict__ H, const float* __restrict__ A1,
    const float* __restrict__ ab1, float* __restrict__ Si,
    float* __restrict__ Sj) {
    __shared__ float Hs[16][304];
    int tid = threadIdx.x;
    int row0 = blockIdx.x * 16;
    for (int idx = tid; idx < 16 * MEMc; idx += 256) {
        int r = idx / MEMc, c = idx - r * MEMc;
        Hs[r][c] = H[(size_t)(row0 + r) * MEMc + c];
    }
    __syncthreads();
    int c = tid & 63, rg = tid >> 6;
    float si[4] = {}, sj[4] = {};
#pragma unroll 4
    for (int k = 0; k < MEMc; k++) {
        float wa = A1[k * HIDc + c];
        float wb = A1[(k + MEMc) * HIDc + c];
#pragma unroll
        for (int rr = 0; rr < 4; rr++) {
            float hv = Hs[rg * 4 + rr][k];
            si[rr] += hv * wa;
            sj[rr] += hv * wb;
        }
    }
    float abv = ab1[c];
#pragma unroll
    for (int rr = 0; rr < 4; rr++) {
        int r = row0 + rg * 4 + rr;
        Si[(size_t)r * HIDc + c] = si[rr];
        Sj[(size_t)r * HIDc + c] = sj[rr] + abv;
    }
}

// ---------------------------------------------------------------------------
// K3: scores + mask + per-row (max, sum-exp); stores p = exp(logit - rowmax)
// grid = (B, N/16); thread j owns column j, its sj row lives in registers
// ---------------------------------------------------------------------------
__global__ void __launch_bounds__(256) scores_kernel(
    const float* __restrict__ Si, const float* __restrict__ Sj,
    const float* __restrict__ adj, const float* __restrict__ A2,
    const float* __restrict__ ab2p, float* __restrict__ P,
    float* __restrict__ rmx, float* __restrict__ rsm) {
    int b = blockIdx.x, ic = blockIdx.y;
    int j = threadIdx.x;
    int wid = j >> 6, lane = j & 63;
    __shared__ float sis[16][64];
    __shared__ float a2s[64];
    __shared__ float mb[4], sbuf[4];

    float4 sv4[16];
    const float4* sjp = (const float4*)(Sj + ((size_t)b * Nc + j) * HIDc);
#pragma unroll
    for (int q = 0; q < 16; q++) sv4[q] = sjp[q];
    const float* sjv = (const float*)sv4;

    if (j < 64) a2s[j] = A2[j];
    for (int idx = j; idx < 16 * 64; idx += 256) {
        int r = idx >> 6, h = idx & 63;
        sis[r][h] = Si[((size_t)b * Nc + ic * 16 + r) * HIDc + h];
    }
    float ab2v = ab2p[0];
    __syncthreads();

    for (int r = 0; r < 16; r++) {
        int i = ic * 16 + r;
        float acc = 0.f;
#pragma unroll
        for (int h = 0; h < 64; h++) {
            float z = sis[r][h] + sjv[h];
            z = z > 0.f ? z : 0.f;
            acc += z * a2s[h];
        }
        float e = acc + ab2v;
        e = e > 0.f ? e : SLOPEc * e;
        float a = adj[((size_t)b * Nc + i) * Nc + j];
        float lg = (a != 0.f) ? e : NEGc;

        float wm = wredMax(lg);
        if (!lane) mb[wid] = wm;
        __syncthreads();
        float rm = fmaxf(fmaxf(mb[0], mb[1]), fmaxf(mb[2], mb[3]));
        float p = expf(lg - rm);  // masked -> exp(-1e30 - rm) == 0
        P[((size_t)b * Nc + i) * Nc + j] = p;
        float wsum = wredSum(p);
        if (!lane) sbuf[wid] = wsum;
        __syncthreads();
        if (j == 0) {
            rmx[b * Nc + i] = rm;
            rsm[b * Nc + i] = sbuf[0] + sbuf[1] + sbuf[2] + sbuf[3];
        }
    }
}

// ---------------------------------------------------------------------------
// K4: fold per-row stats into per-batch softmax; scale_i = exp(m_i - M)/S
// ---------------------------------------------------------------------------
__global__ void __launch_bounds__(256) merge_softmax_kernel(
    const float* __restrict__ rmx, const float* __restrict__ rsm,
    float* __restrict__ scl) {
    int b = blockIdx.x, t = threadIdx.x;
    int wid = t >> 6, lane = t & 63;
    __shared__ float mb[4], sb[4];
    float m = rmx[b * Nc + t];
    float wm = wredMax(m);
    if (!lane) mb[wid] = wm;
    __syncthreads();
    float M = fmaxf(fmaxf(mb[0], mb[1]), fmaxf(mb[2], mb[3]));
    float s = rsm[b * Nc + t] * expf(m - M);
    float ws = wredSum(s);
    if (!lane) sb[wid] = ws;
    __syncthreads();
    float S = sb[0] + sb[1] + sb[2] + sb[3];
    scl[b * Nc + t] = expf(m - M) / S;
}

// ---------------------------------------------------------------------------
// K5: out[b,i,d] = scale[b,i] * sum_j p[b,i,j] * H[b,j,d]
// grid = (B, N/16), 320 threads (d = 0..299 active), P tile transposed in LDS
// ---------------------------------------------------------------------------
__global__ void __launch_bounds__(320) pv_kernel(
    const float* __restrict__ P, const float* __restrict__ scl,
    const float* __restrict__ H, float* __restrict__ out) {
    int b = blockIdx.x, ic = blockIdx.y;
    __shared__ float Pt[256][20];  // [j][r], row stride 80B (16B aligned)
    for (int idx = threadIdx.x; idx < 16 * 256; idx += 320) {
        int r = idx >> 8, jj = idx & 255;
        Pt[jj][r] = P[((size_t)b * Nc + ic * 16 + r) * Nc + jj];
    }
    __syncthreads();
    int d = threadIdx.x;
    if (d < MEMc) {
        float acc[16] = {};
        const float* Hb = H + (size_t)b * Nc * MEMc + d;
#pragma unroll 2
        for (int jj = 0; jj < 256; jj++) {
            float hv = Hb[(size_t)jj * MEMc];
            const float4* pr = (const float4*)&Pt[jj][0];
            float4 p0 = pr[0], p1 = pr[1], p2 = pr[2], p3 = pr[3];
            acc[0] += p0.x * hv;  acc[1] += p0.y * hv;
            acc[2] += p0.z * hv;  acc[3] += p0.w * hv;
            acc[4] += p1.x * hv;  acc[5] += p1.y * hv;
            acc[6] += p1.z * hv;  acc[7] += p1.w * hv;
            acc[8] += p2.x * hv;  acc[9] += p2.y * hv;
            acc[10] += p2.z * hv; acc[11] += p2.w * hv;
            acc[12] += p3.x * hv; acc[13] += p3.y * hv;
            acc[14] += p3.z * hv; acc[15] += p3.w * hv;
        }
#pragma unroll
        for (int r = 0; r < 16; r++) {
            int i = ic * 16 + r;
            out[((size_t)b * Nc + i) * MEMc + d] = acc[r] * scl[b * Nc + i];
        }
    }
}

// ---------------------------------------------------------------------------
extern "C" void kernel_launch(void* const* d_in, const int* in_sizes, int n_in,
                              void* d_out, int out_size, void* d_ws, size_t ws_size,
                              hipStream_t stream) {
    const float* adj     = (const float*)d_in[0];
    const float* feature = (const float*)d_in[1];
    const float* W0      = (const float*)d_in[2];
    const float* b0      = (const float*)d_in[3];
    const float* W1      = (const float*)d_in[4];
    const float* b1      = (const float*)d_in[5];
    const float* A1      = (const float*)d_in[6];
    const float* ab1     = (const float*)d_in[7];
    const float* A2      = (const float*)d_in[8];
    const float* ab2     = (const float*)d_in[9];

    const int R = Bc * Nc;  // 4096
    float* h   = (float*)d_ws;         // R*300
    float* si  = h   + (size_t)R * MEMc;
    float* sj  = si  + (size_t)R * HIDc;
    float* P   = sj  + (size_t)R * HIDc;           // B*N*N
    float* rmx = P   + (size_t)Bc * Nc * Nc;
    float* rsm = rmx + R;
    float* scl = rsm + R;
    float* x1  = scl + R;              // R*300
    float* outp = (float*)d_out;

    for (int layer = 0; layer < 2; layer++) {
        const float* X  = layer ? x1 : feature;
        const float* Wl = layer ? W1 : W0;
        const float* bl = layer ? b1 : b0;
        int K = layer ? MEMc : INDIM;

        gemm_bias_kernel<<<dim3((MEMc + 63) / 64, R / 64), 256, 0, stream>>>(
            X, Wl, bl, h, R, K, MEMc);
        attproj_kernel<<<R / 16, 256, 0, stream>>>(h, A1, ab1, si, sj);
        scores_kernel<<<dim3(Bc, Nc / 16), 256, 0, stream>>>(
            si, sj, adj, A2, ab2, P, rmx, rsm);
        merge_softmax_kernel<<<Bc, 256, 0, stream>>>(rmx, rsm, scl);
        pv_kernel<<<dim3(Bc, Nc / 16), 320, 0, stream>>>(
            P, scl, h, layer ? outp : x1);
    }
}

// Round 2
// 186.823 us; speedup vs baseline: 1.5468x; 1.5468x over previous
//
#include <hip/hip_runtime.h>
#include <hip/hip_bf16.h>

static constexpr int Bc = 16;
static constexpr int Nc = 256;
static constexpr float NEGc = -1e30f;
static constexpr float SLOPEc = 0.01f;

using f32x4 = __attribute__((ext_vector_type(4))) float;
using s16x8 = __attribute__((ext_vector_type(8))) short;
using s16x4 = __attribute__((ext_vector_type(4))) short;

__device__ __forceinline__ void mfma16(f32x4& d, s16x8 a, s16x8 b) {
    // D = A(16x32) * B(32x16) + D ; operand layout: A row=lane&15, k=(lane>>4)*8+reg
    // B col=lane&15, k=(lane>>4)*8+reg ; C/D col=lane&15, row=(lane>>4)*4+reg
    asm("v_mfma_f32_16x16x32_bf16 %0, %1, %2, %0" : "+v"(d) : "v"(a), "v"(b));
}

__device__ __forceinline__ void split2(float v, ushort& hh, ushort& ll) {
    unsigned u = __float_as_uint(v);
    float r = v - __uint_as_float(u & 0xFFFF0000u);   // exact residual
    hh = (ushort)(u >> 16);
    ll = (ushort)(__float_as_uint(r) >> 16);
}

__device__ __forceinline__ float wredMax(float v) {
#pragma unroll
    for (int o = 32; o; o >>= 1) v = fmaxf(v, __shfl_xor(v, o, 64));
    return v;
}
__device__ __forceinline__ float wredSum(float v) {
#pragma unroll
    for (int o = 32; o; o >>= 1) v += __shfl_xor(v, o, 64);
    return v;
}

// ---------------------------------------------------------------------------
// Converters into k-chunked bf16 hi/lo layout: T[(k>>3)][COLS][8] (+zero pad)
// ---------------------------------------------------------------------------
__global__ void convert_w(const float* __restrict__ W, int K, int Kp,
                          ushort* __restrict__ Th, ushort* __restrict__ Tl) {
    int idx = blockIdx.x * 256 + threadIdx.x;
    if (idx >= Kp * 320) return;
    int k = idx / 320, c = idx - k * 320;
    float v = (k < K && c < 300) ? W[(size_t)k * 300 + c] : 0.f;
    ushort hh, ll; split2(v, hh, ll);
    int dst = (k >> 3) * 2560 + c * 8 + (k & 7);
    Th[dst] = hh; Tl[dst] = ll;
}

__global__ void convert_a1(const float* __restrict__ A1,
                           ushort* __restrict__ Th, ushort* __restrict__ Tl) {
    int idx = blockIdx.x * 256 + threadIdx.x;   // 320*128
    if (idx >= 320 * 128) return;
    int k = idx >> 7, c = idx & 127;
    float v = 0.f;
    if (k < 300) v = (c < 64) ? A1[(size_t)k * 64 + c] : A1[(size_t)(300 + k) * 64 + (c - 64)];
    ushort hh, ll; split2(v, hh, ll);
    int dst = (k >> 3) * 1024 + c * 8 + (k & 7);
    Th[dst] = hh; Tl[dst] = ll;
}

__global__ void convert_h(const float* __restrict__ H,
                          ushort* __restrict__ Th, ushort* __restrict__ Tl) {
    int idx = blockIdx.x * 256 + threadIdx.x;   // 16*256*320
    if (idx >= Bc * Nc * 320) return;
    int c = idx % 320;
    int k = (idx / 320) & 255;
    int b = idx / (320 * 256);
    float v = (c < 300) ? H[(size_t)(b * 256 + k) * 320 + c] : 0.f;
    ushort hh, ll; split2(v, hh, ll);
    int dst = b * 81920 + (k >> 3) * 2560 + c * 8 + (k & 7);
    Th[dst] = hh; Tl[dst] = ll;
}

// ---------------------------------------------------------------------------
// Generic batched GEMM: out = split3(A) @ (Wh+Wl) [+bias] [*scl per row]
// A fp32 [rows][AS] split to bf16 hi/lo in-kernel. Tile 128x64, 4 waves (2x2),
// wave tile 64x32 = 4x2 fragments of 16x16x32.
// ---------------------------------------------------------------------------
__global__ void __launch_bounds__(256) mfma_gemm(
    const float* __restrict__ A, long long Abstr, int AS, int Kp,
    const ushort* __restrict__ Wh, const ushort* __restrict__ Wl,
    long long Wbstr, int WCOLS,
    const float* __restrict__ bias,
    float* __restrict__ out, long long Obstr, int OS,
    const float* __restrict__ scl, int Sbstr, int colmax) {
    __shared__ __align__(16) short Ah[4096], Al[4096];   // [4 chunk][128 row][8]
    __shared__ __align__(16) short Bh[2048], Bl[2048];   // [4 chunk][64 col][8]
    const int tid = threadIdx.x;
    const int lane = tid & 63, wave = tid >> 6;
    const int wm = wave >> 1, wn = wave & 1;
    const int row0 = blockIdx.y * 128, col0 = blockIdx.x * 64;
    const int bz = blockIdx.z;

    const int arow = tid >> 1;
    const int ahalf = (tid & 1) << 4;
    const int bchunk = tid >> 6, bcol = tid & 63;
    const int bsel = (bchunk * 64 + bcol) * 8;
    const int m = lane & 15, kch = lane >> 4;

    const float* Ab = A + (size_t)bz * Abstr + (size_t)(row0 + arow) * AS + ahalf;
    const ushort* Whb = Wh + (size_t)bz * Wbstr;
    const ushort* Wlb = Wl + (size_t)bz * Wbstr;

    f32x4 acc[4][2];
#pragma unroll
    for (int i = 0; i < 4; i++)
#pragma unroll
        for (int j = 0; j < 2; j++)
#pragma unroll
            for (int e = 0; e < 4; e++) acc[i][j][e] = 0.f;

    for (int k0 = 0; k0 < Kp; k0 += 32) {
        float4 fa0 = *(const float4*)(Ab + k0);
        float4 fa1 = *(const float4*)(Ab + k0 + 4);
        float4 fa2 = *(const float4*)(Ab + k0 + 8);
        float4 fa3 = *(const float4*)(Ab + k0 + 12);
        size_t boff = (size_t)((k0 >> 3) + bchunk) * WCOLS * 8 + (size_t)(col0 + bcol) * 8;
        s16x8 bhv = *(const s16x8*)(Whb + boff);
        s16x8 blv = *(const s16x8*)(Wlb + boff);
        __syncthreads();   // previous iteration's fragment reads done
        float fv[16];
        *(float4*)&fv[0] = fa0; *(float4*)&fv[4] = fa1;
        *(float4*)&fv[8] = fa2; *(float4*)&fv[12] = fa3;
#pragma unroll
        for (int q = 0; q < 4; q++) {
            s16x4 hi, lo;
#pragma unroll
            for (int e = 0; e < 4; e++) {
                ushort hh, ll;
                split2(fv[q * 4 + e], hh, ll);
                hi[e] = (short)hh; lo[e] = (short)ll;
            }
            int kq = ahalf + q * 4;
            int base = (((kq >> 3) << 7) + arow) * 8 + (kq & 7);
            *(s16x4*)&Ah[base] = hi;
            *(s16x4*)&Al[base] = lo;
        }
        *(s16x8*)&Bh[bsel] = bhv;
        *(s16x8*)&Bl[bsel] = blv;
        __syncthreads();
        s16x8 Afh[4], Afl[4], Bfh[2], Bfl[2];
#pragma unroll
        for (int fr = 0; fr < 4; fr++) {
            int off = ((kch << 7) + wm * 64 + fr * 16 + m) * 8;
            Afh[fr] = *(const s16x8*)&Ah[off];
            Afl[fr] = *(const s16x8*)&Al[off];
        }
#pragma unroll
        for (int fc = 0; fc < 2; fc++) {
            int off = ((kch << 6) + wn * 32 + fc * 16 + m) * 8;
            Bfh[fc] = *(const s16x8*)&Bh[off];
            Bfl[fc] = *(const s16x8*)&Bl[off];
        }
#pragma unroll
        for (int fr = 0; fr < 4; fr++)
#pragma unroll
            for (int fc = 0; fc < 2; fc++) {
                mfma16(acc[fr][fc], Afh[fr], Bfh[fc]);
                mfma16(acc[fr][fc], Afl[fr], Bfh[fc]);
                mfma16(acc[fr][fc], Afh[fr], Bfl[fc]);
            }
    }
    asm volatile("s_nop 7\ns_nop 7\ns_nop 7" ::);   // MFMA -> VALU hazard guard
    float* ob = out + (size_t)bz * Obstr;
    const float* sb = scl ? scl + (size_t)bz * Sbstr : nullptr;
#pragma unroll
    for (int fr = 0; fr < 4; fr++) {
        int rbase = row0 + wm * 64 + fr * 16 + (kch << 2);
#pragma unroll
        for (int fc = 0; fc < 2; fc++) {
            int col = col0 + wn * 32 + fc * 16 + m;
            if (col < colmax) {
                float bv = bias ? bias[col] : 0.f;
#pragma unroll
                for (int e = 0; e < 4; e++) {
                    float v = acc[fr][fc][e] + bv;
                    if (sb) v *= sb[rbase + e];
                    ob[(size_t)(rbase + e) * OS + col] = v;
                }
            }
        }
    }
}

// ---------------------------------------------------------------------------
// scores: e(i,j) = leaky(sum_h relu(si+sj+ab1)*a2 + ab2), mask, per-row
// (max, sum-exp), P = exp(e - rowmax). 8-row tiles, grid (16, 32).
// ---------------------------------------------------------------------------
__global__ void __launch_bounds__(256) scores_kernel(
    const float* __restrict__ SS,    // [4096][128] = si | sj
    const float* __restrict__ adj,
    const float* __restrict__ A2, const float* __restrict__ ab1,
    const float* __restrict__ ab2p,
    float* __restrict__ P, float* __restrict__ rmx, float* __restrict__ rsm) {
    int b = blockIdx.x, ic = blockIdx.y;
    int j = threadIdx.x;
    __shared__ __align__(16) float sis[8][68];
    __shared__ __align__(16) float a2s[64], a1s[64];
    __shared__ __align__(16) float E[8][260];

    if (j < 64) { a2s[j] = A2[j]; a1s[j] = ab1[j]; }
    for (int idx = j; idx < 8 * 64; idx += 256) {
        int r = idx >> 6, h = idx & 63;
        sis[r][h] = SS[((size_t)b * Nc + ic * 8 + r) * 128 + h];
    }
    __syncthreads();

    float4 sv4[16];
    const float4* sjp = (const float4*)(SS + ((size_t)b * Nc + j) * 128 + 64);
#pragma unroll
    for (int q = 0; q < 16; q++) {
        float4 t = sjp[q];
        float4 u = *(const float4*)&a1s[q * 4];
        t.x += u.x; t.y += u.y; t.z += u.z; t.w += u.w;
        sv4[q] = t;
    }
    float acc[8] = {};
    for (int hq = 0; hq < 16; hq++) {
        float4 a2q = *(const float4*)&a2s[hq * 4];
        float4 sjq = sv4[hq];
#pragma unroll
        for (int r = 0; r < 8; r++) {
            float4 siq = *(const float4*)&sis[r][hq * 4];
            acc[r] += a2q.x * fmaxf(siq.x + sjq.x, 0.f)
                    + a2q.y * fmaxf(siq.y + sjq.y, 0.f)
                    + a2q.z * fmaxf(siq.z + sjq.z, 0.f)
                    + a2q.w * fmaxf(siq.w + sjq.w, 0.f);
        }
    }
    float ab2v = ab2p[0];
    const float* adjp = adj + ((size_t)b * Nc + ic * 8) * Nc + j;
#pragma unroll
    for (int r = 0; r < 8; r++) {
        float e = acc[r] + ab2v;
        e = e > 0.f ? e : SLOPEc * e;
        float a = adjp[(size_t)r * Nc];
        E[r][j] = (a != 0.f) ? e : NEGc;
    }
    __syncthreads();
    int wv = j >> 6, lane = j & 63;
#pragma unroll
    for (int rr = 0; rr < 2; rr++) {
        int r = wv * 2 + rr;
        float4 q = *(const float4*)&E[r][lane * 4];
        float m4 = fmaxf(fmaxf(q.x, q.y), fmaxf(q.z, q.w));
        float rm = wredMax(m4);
        float4 p;
        p.x = expf(q.x - rm); p.y = expf(q.y - rm);
        p.z = expf(q.z - rm); p.w = expf(q.w - rm);
        float rs = wredSum(p.x + p.y + p.z + p.w);
        int gi = ic * 8 + r;
        *(float4*)(P + ((size_t)b * Nc + gi) * Nc + lane * 4) = p;
        if (lane == 0) { rmx[b * Nc + gi] = rm; rsm[b * Nc + gi] = rs; }
    }
}

// ---------------------------------------------------------------------------
// fold per-row stats into per-batch flat softmax: scale_i = exp(m_i - M)/S
// ---------------------------------------------------------------------------
__global__ void __launch_bounds__(256) merge_softmax_kernel(
    const float* __restrict__ rmx, const float* __restrict__ rsm,
    float* __restrict__ scl) {
    int b = blockIdx.x, t = threadIdx.x;
    int wid = t >> 6, lane = t & 63;
    __shared__ float mb[4], sb[4];
    float m = rmx[b * Nc + t];
    float wm = wredMax(m);
    if (!lane) mb[wid] = wm;
    __syncthreads();
    float M = fmaxf(fmaxf(mb[0], mb[1]), fmaxf(mb[2], mb[3]));
    float s = rsm[b * Nc + t] * expf(m - M);
    float ws = wredSum(s);
    if (!lane) sb[wid] = ws;
    __syncthreads();
    float S = sb[0] + sb[1] + sb[2] + sb[3];
    scl[b * Nc + t] = expf(m - M) / S;
}

// ---------------------------------------------------------------------------
extern "C" void kernel_launch(void* const* d_in, const int* in_sizes, int n_in,
                              void* d_out, int out_size, void* d_ws, size_t ws_size,
                              hipStream_t stream) {
    const float* adj     = (const float*)d_in[0];
    const float* feature = (const float*)d_in[1];
    const float* W0      = (const float*)d_in[2];
    const float* b0      = (const float*)d_in[3];
    const float* W1      = (const float*)d_in[4];
    const float* b1      = (const float*)d_in[5];
    const float* A1      = (const float*)d_in[6];
    const float* ab1     = (const float*)d_in[7];
    const float* A2      = (const float*)d_in[8];
    const float* ab2     = (const float*)d_in[9];

    char* ws = (char*)d_ws;
    float*  h    = (float*)(ws);                 // 4096x320 fp32   5,242,880 B
    float*  x1   = (float*)(ws + 5242880);       // 4096x320 fp32   5,242,880 B
    float*  sisj = (float*)(ws + 10485760);      // 4096x128 fp32   2,097,152 B
    float*  P    = (float*)(ws + 12582912);      // 16x256x256      4,194,304 B
    float*  rmx  = (float*)(ws + 16777216);
    float*  rsm  = (float*)(ws + 16793600);
    float*  scl  = (float*)(ws + 16809984);
    ushort* Th   = (ushort*)(ws + 16826368);     // shared W/H hi   2,621,440 B
    ushort* Tl   = (ushort*)(ws + 19447808);     // shared W/H lo   2,621,440 B
    ushort* A1h  = (ushort*)(ws + 22069248);     //    81,920 B
    ushort* A1l  = (ushort*)(ws + 22151168);     //    81,920 B  (end 22,233,088)
    float* outp  = (float*)d_out;

    convert_a1<<<160, 256, 0, stream>>>(A1, A1h, A1l);

    for (int L = 0; L < 2; L++) {
        const float* X  = L ? x1 : feature;
        const float* Wf = L ? W1 : W0;
        const float* bf = L ? b1 : b0;
        int K  = L ? 300 : 768;
        int Kp = L ? 320 : 768;
        int AS = L ? 320 : 768;

        convert_w<<<(Kp * 320 + 255) / 256, 256, 0, stream>>>(Wf, K, Kp, Th, Tl);
        // h = X @ W + b
        mfma_gemm<<<dim3(5, 32, 1), 256, 0, stream>>>(
            X, 0, AS, Kp, Th, Tl, 0, 320, bf, h, 0, 320, nullptr, 0, 300);
        // [si|sj] = h @ A1T
        mfma_gemm<<<dim3(2, 32, 1), 256, 0, stream>>>(
            h, 0, 320, 320, A1h, A1l, 0, 128, nullptr, sisj, 0, 128, nullptr, 0, 128);
        scores_kernel<<<dim3(16, 32), 256, 0, stream>>>(
            sisj, adj, A2, ab1, ab2, P, rmx, rsm);
        merge_softmax_kernel<<<16, 256, 0, stream>>>(rmx, rsm, scl);
        convert_h<<<5120, 256, 0, stream>>>(h, Th, Tl);
        // out_rows = scl * (P @ H)
        if (L == 0)
            mfma_gemm<<<dim3(5, 2, 16), 256, 0, stream>>>(
                P, 65536, 256, 256, Th, Tl, 81920, 320, nullptr,
                x1, 81920, 320, scl, 256, 320);
        else
            mfma_gemm<<<dim3(5, 2, 16), 256, 0, stream>>>(
                P, 65536, 256, 256, Th, Tl, 81920, 320, nullptr,
                outp, 76800, 300, scl, 256, 300);
    }
}

// Round 3
// 115.651 us; speedup vs baseline: 2.4987x; 1.6154x over previous
//
#include <hip/hip_runtime.h>
#include <hip/hip_bf16.h>

static constexpr int Bc = 16;
static constexpr int Nc = 256;
static constexpr float NEGc = -1e30f;
static constexpr float SLOPEc = 0.01f;

using f32x4 = __attribute__((ext_vector_type(4))) float;
using s16x8 = __attribute__((ext_vector_type(8))) short;

__device__ __forceinline__ void mfma16(f32x4& d, s16x8 a, s16x8 b) {
    // D = A(16x32)*B(32x16)+D ; A row=lane&15,k=(lane>>4)*8+reg ; B col=lane&15
    // C/D col=lane&15, row=(lane>>4)*4+reg   (validated round 1->2)
    asm("v_mfma_f32_16x16x32_bf16 %0, %1, %2, %0" : "+v"(d) : "v"(a), "v"(b));
}

__device__ __forceinline__ float wredMax(float v) {
#pragma unroll
    for (int o = 32; o; o >>= 1) v = fmaxf(v, __shfl_xor(v, o, 64));
    return v;
}
__device__ __forceinline__ float wredSum(float v) {
#pragma unroll
    for (int o = 32; o; o >>= 1) v += __shfl_xor(v, o, 64);
    return v;
}

// pack hi16 of two fp32 into one u32: [u1.hi16 | u0.hi16]
__device__ __forceinline__ unsigned packhi(unsigned u1, unsigned u0) {
    return __builtin_amdgcn_perm(u1, u0, 0x07060302u);
}

// ---------------------------------------------------------------------------
// Unified weight converter -> k-chunked hi/lo layout T[(k>>3)][cols][8]
// W0: 96x320, W1: 40x320, A1(600x64 -> 320x128): 40x128  (chunk,col) pairs
// ---------------------------------------------------------------------------
__global__ void __launch_bounds__(256) convert_weights(
    const float* __restrict__ W0, const float* __restrict__ W1,
    const float* __restrict__ A1,
    ushort* __restrict__ W0h, ushort* __restrict__ W0l,
    ushort* __restrict__ W1h, ushort* __restrict__ W1l,
    ushort* __restrict__ A1h, ushort* __restrict__ A1l) {
    int off = blockIdx.x * 256 + threadIdx.x;
    if (off >= 48640) return;
    const float* src; ushort *dh, *dl;
    int ch, c, K, cols; bool isA1 = false;
    if (off < 30720) {
        ch = off / 320; c = off - ch * 320; K = 768; cols = 320;
        src = W0; dh = W0h; dl = W0l;
    } else if (off < 43520) {
        off -= 30720;
        ch = off / 320; c = off - ch * 320; K = 300; cols = 320;
        src = W1; dh = W1h; dl = W1l;
    } else {
        off -= 43520;
        ch = off >> 7; c = off & 127; K = 300; cols = 128;
        src = A1; dh = A1h; dl = A1l; isA1 = true;
    }
    float v[8];
#pragma unroll
    for (int e = 0; e < 8; e++) {
        int k = ch * 8 + e;
        float x = 0.f;
        if (k < K) {
            if (isA1) x = (c < 64) ? src[(size_t)k * 64 + c]
                                   : src[(size_t)(300 + k) * 64 + (c - 64)];
            else if (c < 300) x = src[(size_t)k * 300 + c];
        }
        v[e] = x;
    }
    unsigned hu[4], lu[4];
#pragma unroll
    for (int q = 0; q < 4; q++) {
        unsigned u0 = __float_as_uint(v[q * 2]);
        unsigned u1 = __float_as_uint(v[q * 2 + 1]);
        float r0 = v[q * 2] - __uint_as_float(u0 & 0xFFFF0000u);
        float r1 = v[q * 2 + 1] - __uint_as_float(u1 & 0xFFFF0000u);
        hu[q] = packhi(u1, u0);
        lu[q] = packhi(__float_as_uint(r1), __float_as_uint(r0));
    }
    size_t dst = ((size_t)ch * cols + c) * 8;
    *(uint4*)&dh[dst] = make_uint4(hu[0], hu[1], hu[2], hu[3]);
    *(uint4*)&dl[dst] = make_uint4(lu[0], lu[1], lu[2], lu[3]);
}

// ---------------------------------------------------------------------------
// Generic batched GEMM: out = split3(A) @ (Wh+Wl) [+bias] [*softmax-scale]
// [+ hi/lo split copy of out in H layout]. Tile BMx64, 4 waves 2x2,
// 2-phase prefetch (loads for k0+32 issued before ds_read/MFMA of k0).
// ---------------------------------------------------------------------------
template<int BM>
__global__ void __launch_bounds__(256) mfma_gemm(
    const float* __restrict__ A, long long Abstr, int AS, int Kp,
    const ushort* __restrict__ Wh, const ushort* __restrict__ Wl,
    long long Wbstr, int WCOLS,
    const float* __restrict__ bias, int biasN,
    float* __restrict__ out, long long Obstr, int OS, int colmax,
    const float* __restrict__ rmx, const float* __restrict__ rsm,
    ushort* __restrict__ TOh, ushort* __restrict__ TOl) {
    constexpr int TPR = 256 / BM;   // threads per A row
    constexpr int NF  = 32 / TPR;   // fp32 per thread per K-tile
    constexpr int NQ  = NF / 4;
    constexpr int FR  = BM / 32;
    constexpr int FC  = 2;
    constexpr int WROW = BM / 2;

    __shared__ __align__(16) short Ah[BM * 32], Al[BM * 32];
    __shared__ __align__(16) short Bh[2048], Bl[2048];
    __shared__ float sclS[256];
    __shared__ float mb[4], sb[4];

    const int tid = threadIdx.x;
    const int lane = tid & 63, wave = tid >> 6;
    const int wm = wave >> 1, wn = wave & 1;
    const int row0 = blockIdx.y * BM, col0 = blockIdx.x * 64;
    const int bz = blockIdx.z;
    const int m = lane & 15, kch = lane >> 4;

    // fused softmax merge: scale_i = exp(m_i - M)/S for this batch
    if (rmx) {
        float mv = rmx[bz * 256 + tid];
        float wmx = wredMax(mv);
        if (!lane) mb[wave] = wmx;
        __syncthreads();
        float M = fmaxf(fmaxf(mb[0], mb[1]), fmaxf(mb[2], mb[3]));
        float ex = expf(mv - M);
        float ws = wredSum(rsm[bz * 256 + tid] * ex);
        if (!lane) sb[wave] = ws;
        __syncthreads();
        float S = sb[0] + sb[1] + sb[2] + sb[3];
        sclS[tid] = ex / S;
    }

    const int arow = tid / TPR;
    const int aoff = (tid % TPR) * NF;
    const int bchunk = tid >> 6, bcol = tid & 63;
    const int bsel = (bchunk * 64 + bcol) * 8;

    const float* Ab = A + (size_t)bz * Abstr + (size_t)(row0 + arow) * AS + aoff;
    const ushort* Whb = Wh + (size_t)bz * Wbstr;
    const ushort* Wlb = Wl + (size_t)bz * Wbstr;

    f32x4 acc[FR][FC];
#pragma unroll
    for (int i = 0; i < FR; i++)
#pragma unroll
        for (int j = 0; j < FC; j++)
#pragma unroll
            for (int e = 0; e < 4; e++) acc[i][j][e] = 0.f;

    float fa[NF];
    s16x8 bhv, blv;
#pragma unroll
    for (int q = 0; q < NQ; q++) *(float4*)&fa[q * 4] = *(const float4*)(Ab + q * 4);
    {
        size_t boff = (size_t)bchunk * WCOLS * 8 + (size_t)(col0 + bcol) * 8;
        bhv = *(const s16x8*)(Whb + boff);
        blv = *(const s16x8*)(Wlb + boff);
    }

    for (int k0 = 0; k0 < Kp; k0 += 32) {
        __syncthreads();   // prev iteration's fragment reads done
#pragma unroll
        for (int q = 0; q < NQ; q++) {
            unsigned u0 = __float_as_uint(fa[q * 4 + 0]);
            unsigned u1 = __float_as_uint(fa[q * 4 + 1]);
            unsigned u2 = __float_as_uint(fa[q * 4 + 2]);
            unsigned u3 = __float_as_uint(fa[q * 4 + 3]);
            float r0 = fa[q * 4 + 0] - __uint_as_float(u0 & 0xFFFF0000u);
            float r1 = fa[q * 4 + 1] - __uint_as_float(u1 & 0xFFFF0000u);
            float r2 = fa[q * 4 + 2] - __uint_as_float(u2 & 0xFFFF0000u);
            float r3 = fa[q * 4 + 3] - __uint_as_float(u3 & 0xFFFF0000u);
            uint2 th, tl;
            th.x = packhi(u1, u0); th.y = packhi(u3, u2);
            tl.x = packhi(__float_as_uint(r1), __float_as_uint(r0));
            tl.y = packhi(__float_as_uint(r3), __float_as_uint(r2));
            int kq = aoff + q * 4;
            int base = ((kq >> 3) * BM + arow) * 8 + (kq & 7);
            *(uint2*)&Ah[base] = th;
            *(uint2*)&Al[base] = tl;
        }
        *(s16x8*)&Bh[bsel] = bhv;
        *(s16x8*)&Bl[bsel] = blv;
        __syncthreads();
        if (k0 + 32 < Kp) {   // prefetch next K-tile (overlaps ds_read+MFMA below)
#pragma unroll
            for (int q = 0; q < NQ; q++)
                *(float4*)&fa[q * 4] = *(const float4*)(Ab + k0 + 32 + q * 4);
            size_t boff = (size_t)(((k0 + 32) >> 3) + bchunk) * WCOLS * 8
                        + (size_t)(col0 + bcol) * 8;
            bhv = *(const s16x8*)(Whb + boff);
            blv = *(const s16x8*)(Wlb + boff);
        }
        s16x8 Afh[FR], Afl[FR], Bfh[FC], Bfl[FC];
#pragma unroll
        for (int fr = 0; fr < FR; fr++) {
            int off = (kch * BM + wm * WROW + fr * 16 + m) * 8;
            Afh[fr] = *(const s16x8*)&Ah[off];
            Afl[fr] = *(const s16x8*)&Al[off];
        }
#pragma unroll
        for (int fc = 0; fc < FC; fc++) {
            int off = ((kch << 6) + wn * 32 + fc * 16 + m) * 8;
            Bfh[fc] = *(const s16x8*)&Bh[off];
            Bfl[fc] = *(const s16x8*)&Bl[off];
        }
#pragma unroll
        for (int fr = 0; fr < FR; fr++)
#pragma unroll
            for (int fc = 0; fc < FC; fc++) {
                mfma16(acc[fr][fc], Afh[fr], Bfh[fc]);
                mfma16(acc[fr][fc], Afl[fr], Bfh[fc]);
                mfma16(acc[fr][fc], Afh[fr], Bfl[fc]);
            }
    }
    asm volatile("s_nop 7\ns_nop 7\ns_nop 7" ::);   // MFMA -> VALU hazard guard
    float* ob = out + (size_t)bz * Obstr;
#pragma unroll
    for (int fr = 0; fr < FR; fr++) {
        int rbase = row0 + wm * WROW + fr * 16 + (kch << 2);
#pragma unroll
        for (int fc = 0; fc < FC; fc++) {
            int col = col0 + wn * 32 + fc * 16 + m;
            float bv = (bias && col < biasN) ? bias[col] : 0.f;
            float vv[4];
#pragma unroll
            for (int e = 0; e < 4; e++) vv[e] = acc[fr][fc][e] + bv;
            if (rmx) {
#pragma unroll
                for (int e = 0; e < 4; e++) vv[e] *= sclS[(rbase + e) & 255];
            }
            if (col < colmax) {
#pragma unroll
                for (int e = 0; e < 4; e++)
                    ob[(size_t)(rbase + e) * OS + col] = vv[e];
            }
            if (TOh) {   // hi/lo split copy, H layout: [b][k>>3][320 cols][8]
                unsigned u0 = __float_as_uint(vv[0]);
                unsigned u1 = __float_as_uint(vv[1]);
                unsigned u2 = __float_as_uint(vv[2]);
                unsigned u3 = __float_as_uint(vv[3]);
                float r0 = vv[0] - __uint_as_float(u0 & 0xFFFF0000u);
                float r1 = vv[1] - __uint_as_float(u1 & 0xFFFF0000u);
                float r2 = vv[2] - __uint_as_float(u2 & 0xFFFF0000u);
                float r3 = vv[3] - __uint_as_float(u3 & 0xFFFF0000u);
                uint2 th, tl;
                th.x = packhi(u1, u0); th.y = packhi(u3, u2);
                tl.x = packhi(__float_as_uint(r1), __float_as_uint(r0));
                tl.y = packhi(__float_as_uint(r3), __float_as_uint(r2));
                int k = rbase & 255, bb = rbase >> 8;
                size_t dst = (size_t)bb * 81920 + ((size_t)(k >> 3) * 320 + col) * 8 + (k & 7);
                *(uint2*)&TOh[dst] = th;
                *(uint2*)&TOl[dst] = tl;
            }
        }
    }
}

// ---------------------------------------------------------------------------
// scores: e(i,j) = leaky(sum_h relu(si+sj+ab1)*a2 + ab2), mask, per-row
// (max, sum-exp), P = exp(e - rowmax). 8-row tiles, grid (16, 32).
// ---------------------------------------------------------------------------
__global__ void __launch_bounds__(256) scores_kernel(
    const float* __restrict__ SS,    // [4096][128] = si | sj
    const float* __restrict__ adj,
    const float* __restrict__ A2, const float* __restrict__ ab1,
    const float* __restrict__ ab2p,
    float* __restrict__ P, float* __restrict__ rmx, float* __restrict__ rsm) {
    int b = blockIdx.x, ic = blockIdx.y;
    int j = threadIdx.x;
    __shared__ __align__(16) float sis[8][68];
    __shared__ __align__(16) float a2s[64], a1s[64];
    __shared__ __align__(16) float E[8][260];

    if (j < 64) { a2s[j] = A2[j]; a1s[j] = ab1[j]; }
    for (int idx = j; idx < 8 * 64; idx += 256) {
        int r = idx >> 6, h = idx & 63;
        sis[r][h] = SS[((size_t)b * Nc + ic * 8 + r) * 128 + h];
    }
    __syncthreads();

    float4 sv4[16];
    const float4* sjp = (const float4*)(SS + ((size_t)b * Nc + j) * 128 + 64);
#pragma unroll
    for (int q = 0; q < 16; q++) {
        float4 t = sjp[q];
        float4 u = *(const float4*)&a1s[q * 4];
        t.x += u.x; t.y += u.y; t.z += u.z; t.w += u.w;
        sv4[q] = t;
    }
    float acc[8] = {};
    for (int hq = 0; hq < 16; hq++) {
        float4 a2q = *(const float4*)&a2s[hq * 4];
        float4 sjq = sv4[hq];
#pragma unroll
        for (int r = 0; r < 8; r++) {
            float4 siq = *(const float4*)&sis[r][hq * 4];
            acc[r] += a2q.x * fmaxf(siq.x + sjq.x, 0.f)
                    + a2q.y * fmaxf(siq.y + sjq.y, 0.f)
                    + a2q.z * fmaxf(siq.z + sjq.z, 0.f)
                    + a2q.w * fmaxf(siq.w + sjq.w, 0.f);
        }
    }
    float ab2v = ab2p[0];
    const float* adjp = adj + ((size_t)b * Nc + ic * 8) * Nc + j;
#pragma unroll
    for (int r = 0; r < 8; r++) {
        float e = acc[r] + ab2v;
        e = e > 0.f ? e : SLOPEc * e;
        float a = adjp[(size_t)r * Nc];
        E[r][j] = (a != 0.f) ? e : NEGc;
    }
    __syncthreads();
    int wv = j >> 6, lane = j & 63;
#pragma unroll
    for (int rr = 0; rr < 2; rr++) {
        int r = wv * 2 + rr;
        float4 q = *(const float4*)&E[r][lane * 4];
        float m4 = fmaxf(fmaxf(q.x, q.y), fmaxf(q.z, q.w));
        float rm = wredMax(m4);
        float4 p;
        p.x = expf(q.x - rm); p.y = expf(q.y - rm);
        p.z = expf(q.z - rm); p.w = expf(q.w - rm);
        float rs = wredSum(p.x + p.y + p.z + p.w);
        int gi = ic * 8 + r;
        *(float4*)(P + ((size_t)b * Nc + gi) * Nc + lane * 4) = p;
        if (lane == 0) { rmx[b * Nc + gi] = rm; rsm[b * Nc + gi] = rs; }
    }
}

// ---------------------------------------------------------------------------
extern "C" void kernel_launch(void* const* d_in, const int* in_sizes, int n_in,
                              void* d_out, int out_size, void* d_ws, size_t ws_size,
                              hipStream_t stream) {
    const float* adj     = (const float*)d_in[0];
    const float* feature = (const float*)d_in[1];
    const float* W0      = (const float*)d_in[2];
    const float* b0      = (const float*)d_in[3];
    const float* W1      = (const float*)d_in[4];
    const float* b1      = (const float*)d_in[5];
    const float* A1      = (const float*)d_in[6];
    const float* ab1     = (const float*)d_in[7];
    const float* A2      = (const float*)d_in[8];
    const float* ab2     = (const float*)d_in[9];

    char* ws = (char*)d_ws;
    float*  h    = (float*)(ws);                  // 4096x320
    float*  x1   = (float*)(ws + 5242880);        // 4096x320
    float*  sisj = (float*)(ws + 10485760);       // 4096x128
    float*  P    = (float*)(ws + 12582912);       // 16x256x256
    float*  rmx  = (float*)(ws + 16777216);
    float*  rsm  = (float*)(ws + 16793600);
    ushort* W0h  = (ushort*)(ws + 16809984);
    ushort* W0l  = (ushort*)(ws + 17301504);
    ushort* W1h  = (ushort*)(ws + 17793024);
    ushort* W1l  = (ushort*)(ws + 17997824);
    ushort* A1h  = (ushort*)(ws + 18202624);
    ushort* A1l  = (ushort*)(ws + 18284544);
    ushort* Hh   = (ushort*)(ws + 18366464);      // 16 x [32][320][8]
    ushort* Hl   = (ushort*)(ws + 20987904);      // end 23,609,344
    float* outp  = (float*)d_out;

    convert_weights<<<190, 256, 0, stream>>>(W0, W1, A1, W0h, W0l, W1h, W1l, A1h, A1l);

    for (int L = 0; L < 2; L++) {
        const float* X  = L ? x1 : feature;
        const ushort* Wfh = L ? W1h : W0h;
        const ushort* Wfl = L ? W1l : W0l;
        const float* bf = L ? b1 : b0;
        int Kp = L ? 320 : 768;
        int AS = L ? 320 : 768;

        // h = X @ W + b   (+ hi/lo split copy for the PV B-operand)
        mfma_gemm<64><<<dim3(5, 64, 1), 256, 0, stream>>>(
            X, 0, AS, Kp, Wfh, Wfl, 0, 320, bf, 300,
            h, 0, 320, 320, nullptr, nullptr, Hh, Hl);
        // [si|sj] = h @ A1T
        mfma_gemm<64><<<dim3(2, 64, 1), 256, 0, stream>>>(
            h, 0, 320, 320, A1h, A1l, 0, 128, nullptr, 0,
            sisj, 0, 128, 128, nullptr, nullptr, nullptr, nullptr);
        scores_kernel<<<dim3(16, 32), 256, 0, stream>>>(
            sisj, adj, A2, ab1, ab2, P, rmx, rsm);
        // out_rows = softmax_scale * (P @ H)   (merge fused in prologue)
        if (L == 0)
            mfma_gemm<64><<<dim3(5, 4, 16), 256, 0, stream>>>(
                P, 65536, 256, 256, Hh, Hl, 81920, 320, nullptr, 0,
                x1, 81920, 320, 320, rmx, rsm, nullptr, nullptr);
        else
            mfma_gemm<64><<<dim3(5, 4, 16), 256, 0, stream>>>(
                P, 65536, 256, 256, Hh, Hl, 81920, 320, nullptr, 0,
                outp, 76800, 300, 300, rmx, rsm, nullptr, nullptr);
    }
}

// Round 4
// 103.630 us; speedup vs baseline: 2.7886x; 1.1160x over previous
//
#include <hip/hip_runtime.h>
#include <hip/hip_bf16.h>

static constexpr int Bc = 16;
static constexpr int Nc = 256;
static constexpr float NEGc = -1e30f;
static constexpr float SLOPEc = 0.01f;

using f32x4 = __attribute__((ext_vector_type(4))) float;
using s16x8 = __attribute__((ext_vector_type(8))) short;

__device__ __forceinline__ void mfma16(f32x4& d, s16x8 a, s16x8 b) {
    // D = A(16x32)*B(32x16)+D ; A row=lane&15,k=(lane>>4)*8+reg ; B col=lane&15
    // C/D col=lane&15, row=(lane>>4)*4+reg   (validated rounds 1-3)
    asm("v_mfma_f32_16x16x32_bf16 %0, %1, %2, %0" : "+v"(d) : "v"(a), "v"(b));
}

__device__ __forceinline__ float wredMax(float v) {
#pragma unroll
    for (int o = 32; o; o >>= 1) v = fmaxf(v, __shfl_xor(v, o, 64));
    return v;
}
__device__ __forceinline__ float wredSum(float v) {
#pragma unroll
    for (int o = 32; o; o >>= 1) v += __shfl_xor(v, o, 64);
    return v;
}

// pack hi16 of two fp32 into one u32: [u1.hi16 | u0.hi16]
__device__ __forceinline__ unsigned packhi(unsigned u1, unsigned u0) {
    return __builtin_amdgcn_perm(u1, u0, 0x07060302u);
}

// ---------------------------------------------------------------------------
// convert_all: builds fused split weights F = [ W | W@A1parts ] (448 cols,
// k-chunked hi/lo layout [chunk][448][8]) and fused bias vectors (448):
//   cols 0-319: W cols (pad>=300 zero), bias = b (pad 0)
//   cols 320-383: W@Wa, bias = b@Wa
//   cols 384-447: W@Wb, bias = b@Wb + ab1
// ---------------------------------------------------------------------------
__global__ void __launch_bounds__(256) convert_all(
    const float* __restrict__ W0, const float* __restrict__ b0,
    const float* __restrict__ W1, const float* __restrict__ b1,
    const float* __restrict__ A1, const float* __restrict__ ab1,
    ushort* __restrict__ F0h, ushort* __restrict__ F0l,
    ushort* __restrict__ F1h, ushort* __restrict__ F1l,
    float* __restrict__ bias0, float* __restrict__ bias1) {
    int idx = blockIdx.x * 256 + threadIdx.x;
    if (idx >= 79232) return;

    if (idx < 43520) {
        // W-split sections: A=[0,30720) W0, B=[30720,43520) W1
        const float* src; ushort *dh, *dl; int K, ch, c;
        if (idx < 30720) { src = W0; dh = F0h; dl = F0l; K = 768;
                           ch = idx / 320; c = idx - ch * 320; }
        else { int off = idx - 30720; src = W1; dh = F1h; dl = F1l; K = 300;
               ch = off / 320; c = off - ch * 320; }
        float v[8];
#pragma unroll
        for (int e = 0; e < 8; e++) {
            int k = ch * 8 + e;
            v[e] = (k < K && c < 300) ? src[(size_t)k * 300 + c] : 0.f;
        }
        unsigned hu[4], lu[4];
#pragma unroll
        for (int q = 0; q < 4; q++) {
            unsigned u0 = __float_as_uint(v[q * 2]);
            unsigned u1 = __float_as_uint(v[q * 2 + 1]);
            float r0 = v[q * 2] - __uint_as_float(u0 & 0xFFFF0000u);
            float r1 = v[q * 2 + 1] - __uint_as_float(u1 & 0xFFFF0000u);
            hu[q] = packhi(u1, u0);
            lu[q] = packhi(__float_as_uint(r1), __float_as_uint(r0));
        }
        size_t dst = ((size_t)ch * 448 + c) * 8;
        *(uint4*)&dh[dst] = make_uint4(hu[0], hu[1], hu[2], hu[3]);
        *(uint4*)&dl[dst] = make_uint4(lu[0], lu[1], lu[2], lu[3]);
    } else if (idx < 78336) {
        // WA sections: C=[43520,68096) WA0, D=[68096,78336) WA1
        const float* Wsrc; ushort *dh, *dl; int K, ch, c, eh;
        if (idx < 68096) {
            int off = idx - 43520; Wsrc = W0; dh = F0h; dl = F0l; K = 768;
            ch = off >> 8; int rem = off & 255; c = rem >> 1; eh = rem & 1;
        } else {
            int off = idx - 68096; Wsrc = W1; dh = F1h; dl = F1l; K = 300;
            ch = off >> 8; int rem = off & 255; c = rem >> 1; eh = rem & 1;
        }
        const float* Wr[4]; float val[4];
#pragma unroll
        for (int i = 0; i < 4; i++) {
            int k = ch * 8 + eh * 4 + i;
            int kc = k < K ? k : 0;
            Wr[i] = Wsrc + (size_t)kc * 300;
            val[i] = (k < K) ? 1.f : 0.f;
        }
        const float* a1c = (c < 64) ? (A1 + c) : (A1 + 300 * 64 + (c - 64));
        float acc[4] = {};
        for (int m = 0; m < 300; m++) {
            float av = a1c[(size_t)m * 64];
#pragma unroll
            for (int i = 0; i < 4; i++) acc[i] += Wr[i][m] * av;
        }
#pragma unroll
        for (int i = 0; i < 4; i++) acc[i] *= val[i];
        unsigned hu[2], lu[2];
#pragma unroll
        for (int q = 0; q < 2; q++) {
            unsigned u0 = __float_as_uint(acc[q * 2]);
            unsigned u1 = __float_as_uint(acc[q * 2 + 1]);
            float r0 = acc[q * 2] - __uint_as_float(u0 & 0xFFFF0000u);
            float r1 = acc[q * 2 + 1] - __uint_as_float(u1 & 0xFFFF0000u);
            hu[q] = packhi(u1, u0);
            lu[q] = packhi(__float_as_uint(r1), __float_as_uint(r0));
        }
        size_t dst = ((size_t)ch * 448 + 320 + c) * 8 + eh * 4;
        *(uint2*)&dh[dst] = make_uint2(hu[0], hu[1]);
        *(uint2*)&dl[dst] = make_uint2(lu[0], lu[1]);
    } else {
        // bias fold: E=[78336,79232)
        int off = idx - 78336;
        int layer = off / 448, col = off - layer * 448;
        const float* b = layer ? b1 : b0;
        float v;
        if (col < 320) {
            v = (col < 300) ? b[col] : 0.f;
        } else {
            int cc = col - 320;
            const float* a1c = (cc < 64) ? (A1 + cc) : (A1 + 300 * 64 + (cc - 64));
            float s = 0.f;
            for (int m = 0; m < 300; m++) s += b[m] * a1c[(size_t)m * 64];
            v = s + ((cc >= 64) ? ab1[cc - 64] : 0.f);
        }
        (layer ? bias1 : bias0)[col] = v;
    }
}

// ---------------------------------------------------------------------------
// Generic batched GEMM: out = split3(A) @ (Wh+Wl) [+bias]
// Epilogue routes per col-tile: col>=320 -> fp32 sisj write; TOh set ->
// hi/lo split write (H layout); else fp32 out [*softmax-scale via rmx/rsm].
// Tile 64x64, 4 waves 2x2, 2-phase prefetch.
// ---------------------------------------------------------------------------
__global__ void __launch_bounds__(256) mfma_gemm(
    const float* __restrict__ A, long long Abstr, int AS, int Kp,
    const ushort* __restrict__ Wh, const ushort* __restrict__ Wl,
    long long Wbstr, int WCOLS,
    const float* __restrict__ bias,
    float* __restrict__ out, long long Obstr, int OS, int colmax,
    const float* __restrict__ rmx, const float* __restrict__ rsm,
    ushort* __restrict__ TOh, ushort* __restrict__ TOl,
    float* __restrict__ sisjOut) {
    constexpr int BM = 64;
    __shared__ __align__(16) short Ah[2048], Al[2048];   // [4][64][8]
    __shared__ __align__(16) short Bh[2048], Bl[2048];   // [4][64][8]
    __shared__ float sclS[256];
    __shared__ float mb[4], sb[4];

    const int tid = threadIdx.x;
    const int lane = tid & 63, wave = tid >> 6;
    const int wm = wave >> 1, wn = wave & 1;
    const int row0 = blockIdx.y * BM, col0 = blockIdx.x * 64;
    const int bz = blockIdx.z;
    const int m = lane & 15, kch = lane >> 4;

    if (rmx) {   // fused flat-softmax merge for this batch
        float mv = rmx[bz * 256 + tid];
        float wmx = wredMax(mv);
        if (!lane) mb[wave] = wmx;
        __syncthreads();
        float M = fmaxf(fmaxf(mb[0], mb[1]), fmaxf(mb[2], mb[3]));
        float ex = expf(mv - M);
        float ws = wredSum(rsm[bz * 256 + tid] * ex);
        if (!lane) sb[wave] = ws;
        __syncthreads();
        float S = sb[0] + sb[1] + sb[2] + sb[3];
        sclS[tid] = ex / S;
    }

    const int arow = tid >> 2;            // 64 rows
    const int aoff = (tid & 3) * 8;       // 8 fp32 per thread
    const int bchunk = tid >> 6, bcol = tid & 63;
    const int bsel = (bchunk * 64 + bcol) * 8;

    const float* Ab = A + (size_t)bz * Abstr + (size_t)(row0 + arow) * AS + aoff;
    const ushort* Whb = Wh + (size_t)bz * Wbstr;
    const ushort* Wlb = Wl + (size_t)bz * Wbstr;

    f32x4 acc[2][2];
#pragma unroll
    for (int i = 0; i < 2; i++)
#pragma unroll
        for (int j = 0; j < 2; j++)
#pragma unroll
            for (int e = 0; e < 4; e++) acc[i][j][e] = 0.f;

    float fa[8];
    s16x8 bhv, blv;
    *(float4*)&fa[0] = *(const float4*)(Ab);
    *(float4*)&fa[4] = *(const float4*)(Ab + 4);
    {
        size_t boff = (size_t)bchunk * WCOLS * 8 + (size_t)(col0 + bcol) * 8;
        bhv = *(const s16x8*)(Whb + boff);
        blv = *(const s16x8*)(Wlb + boff);
    }

    for (int k0 = 0; k0 < Kp; k0 += 32) {
        __syncthreads();
#pragma unroll
        for (int q = 0; q < 2; q++) {
            unsigned u0 = __float_as_uint(fa[q * 4 + 0]);
            unsigned u1 = __float_as_uint(fa[q * 4 + 1]);
            unsigned u2 = __float_as_uint(fa[q * 4 + 2]);
            unsigned u3 = __float_as_uint(fa[q * 4 + 3]);
            float r0 = fa[q * 4 + 0] - __uint_as_float(u0 & 0xFFFF0000u);
            float r1 = fa[q * 4 + 1] - __uint_as_float(u1 & 0xFFFF0000u);
            float r2 = fa[q * 4 + 2] - __uint_as_float(u2 & 0xFFFF0000u);
            float r3 = fa[q * 4 + 3] - __uint_as_float(u3 & 0xFFFF0000u);
            uint2 th, tl;
            th.x = packhi(u1, u0); th.y = packhi(u3, u2);
            tl.x = packhi(__float_as_uint(r1), __float_as_uint(r0));
            tl.y = packhi(__float_as_uint(r3), __float_as_uint(r2));
            int kq = aoff + q * 4;
            int base = ((kq >> 3) * BM + arow) * 8 + (kq & 7);
            *(uint2*)&Ah[base] = th;
            *(uint2*)&Al[base] = tl;
        }
        *(s16x8*)&Bh[bsel] = bhv;
        *(s16x8*)&Bl[bsel] = blv;
        __syncthreads();
        if (k0 + 32 < Kp) {   // prefetch next K-tile
            *(float4*)&fa[0] = *(const float4*)(Ab + k0 + 32);
            *(float4*)&fa[4] = *(const float4*)(Ab + k0 + 36);
            size_t boff = (size_t)(((k0 + 32) >> 3) + bchunk) * WCOLS * 8
                        + (size_t)(col0 + bcol) * 8;
            bhv = *(const s16x8*)(Whb + boff);
            blv = *(const s16x8*)(Wlb + boff);
        }
        s16x8 Afh[2], Afl[2], Bfh[2], Bfl[2];
#pragma unroll
        for (int fr = 0; fr < 2; fr++) {
            int off = (kch * BM + wm * 32 + fr * 16 + m) * 8;
            Afh[fr] = *(const s16x8*)&Ah[off];
            Afl[fr] = *(const s16x8*)&Al[off];
        }
#pragma unroll
        for (int fc = 0; fc < 2; fc++) {
            int off = ((kch << 6) + wn * 32 + fc * 16 + m) * 8;
            Bfh[fc] = *(const s16x8*)&Bh[off];
            Bfl[fc] = *(const s16x8*)&Bl[off];
        }
#pragma unroll
        for (int fr = 0; fr < 2; fr++)
#pragma unroll
            for (int fc = 0; fc < 2; fc++) {
                mfma16(acc[fr][fc], Afh[fr], Bfh[fc]);
                mfma16(acc[fr][fc], Afl[fr], Bfh[fc]);
                mfma16(acc[fr][fc], Afh[fr], Bfl[fc]);
            }
    }
    asm volatile("s_nop 7\ns_nop 7\ns_nop 7" ::);   // MFMA -> VALU hazard guard
    float* ob = out ? out + (size_t)bz * Obstr : nullptr;
#pragma unroll
    for (int fr = 0; fr < 2; fr++) {
        int rbase = row0 + wm * 32 + fr * 16 + (kch << 2);
#pragma unroll
        for (int fc = 0; fc < 2; fc++) {
            int col = col0 + wn * 32 + fc * 16 + m;
            float bv = bias ? bias[col] : 0.f;
            float vv[4];
#pragma unroll
            for (int e = 0; e < 4; e++) vv[e] = acc[fr][fc][e] + bv;
            if (rmx) {
#pragma unroll
                for (int e = 0; e < 4; e++) vv[e] *= sclS[(rbase + e) & 255];
            }
            if (sisjOut && col >= 320) {
#pragma unroll
                for (int e = 0; e < 4; e++)
                    sisjOut[(size_t)(rbase + e) * 128 + (col - 320)] = vv[e];
            } else if (TOh) {   // hi/lo split write, H layout [b][k>>3][320][8]
                unsigned u0 = __float_as_uint(vv[0]);
                unsigned u1 = __float_as_uint(vv[1]);
                unsigned u2 = __float_as_uint(vv[2]);
                unsigned u3 = __float_as_uint(vv[3]);
                float r0 = vv[0] - __uint_as_float(u0 & 0xFFFF0000u);
                float r1 = vv[1] - __uint_as_float(u1 & 0xFFFF0000u);
                float r2 = vv[2] - __uint_as_float(u2 & 0xFFFF0000u);
                float r3 = vv[3] - __uint_as_float(u3 & 0xFFFF0000u);
                uint2 th, tl;
                th.x = packhi(u1, u0); th.y = packhi(u3, u2);
                tl.x = packhi(__float_as_uint(r1), __float_as_uint(r0));
                tl.y = packhi(__float_as_uint(r3), __float_as_uint(r2));
                int k = rbase & 255, bb = rbase >> 8;
                size_t dst = (size_t)bb * 81920 + ((size_t)(k >> 3) * 320 + col) * 8 + (k & 7);
                *(uint2*)&TOh[dst] = th;
                *(uint2*)&TOl[dst] = tl;
            } else if (ob && col < colmax) {
#pragma unroll
                for (int e = 0; e < 4; e++)
                    ob[(size_t)(rbase + e) * OS + col] = vv[e];
            }
        }
    }
}

// ---------------------------------------------------------------------------
// scores: e(i,j) = leaky(sum_h relu(si+sj)*a2 + ab2), mask, per-row
// (max, sum-exp), P = exp(e - rowmax). 8-row tiles, grid (16, 32).
// (ab1 is folded into sj via the fused bias.)
// ---------------------------------------------------------------------------
__global__ void __launch_bounds__(256) scores_kernel(
    const float* __restrict__ SS,    // [4096][128] = si | sj
    const float* __restrict__ adj,
    const float* __restrict__ A2, const float* __restrict__ ab2p,
    float* __restrict__ P, float* __restrict__ rmx, float* __restrict__ rsm) {
    int b = blockIdx.x, ic = blockIdx.y;
    int j = threadIdx.x;
    __shared__ __align__(16) float sis[8][68];
    __shared__ __align__(16) float a2s[64];
    __shared__ __align__(16) float E[8][260];

    if (j < 64) a2s[j] = A2[j];
    for (int idx = j; idx < 8 * 64; idx += 256) {
        int r = idx >> 6, h = idx & 63;
        sis[r][h] = SS[((size_t)b * Nc + ic * 8 + r) * 128 + h];
    }
    __syncthreads();

    float4 sv4[16];
    const float4* sjp = (const float4*)(SS + ((size_t)b * Nc + j) * 128 + 64);
#pragma unroll
    for (int q = 0; q < 16; q++) sv4[q] = sjp[q];
    float acc[8] = {};
    for (int hq = 0; hq < 16; hq++) {
        float4 a2q = *(const float4*)&a2s[hq * 4];
        float4 sjq = sv4[hq];
#pragma unroll
        for (int r = 0; r < 8; r++) {
            float4 siq = *(const float4*)&sis[r][hq * 4];
            acc[r] += a2q.x * fmaxf(siq.x + sjq.x, 0.f)
                    + a2q.y * fmaxf(siq.y + sjq.y, 0.f)
                    + a2q.z * fmaxf(siq.z + sjq.z, 0.f)
                    + a2q.w * fmaxf(siq.w + sjq.w, 0.f);
        }
    }
    float ab2v = ab2p[0];
    const float* adjp = adj + ((size_t)b * Nc + ic * 8) * Nc + j;
#pragma unroll
    for (int r = 0; r < 8; r++) {
        float e = acc[r] + ab2v;
        e = e > 0.f ? e : SLOPEc * e;
        float a = adjp[(size_t)r * Nc];
        E[r][j] = (a != 0.f) ? e : NEGc;
    }
    __syncthreads();
    int wv = j >> 6, lane = j & 63;
#pragma unroll
    for (int rr = 0; rr < 2; rr++) {
        int r = wv * 2 + rr;
        float4 q = *(const float4*)&E[r][lane * 4];
        float m4 = fmaxf(fmaxf(q.x, q.y), fmaxf(q.z, q.w));
        float rm = wredMax(m4);
        float4 p;
        p.x = expf(q.x - rm); p.y = expf(q.y - rm);
        p.z = expf(q.z - rm); p.w = expf(q.w - rm);
        float rs = wredSum(p.x + p.y + p.z + p.w);
        int gi = ic * 8 + r;
        *(float4*)(P + ((size_t)b * Nc + gi) * Nc + lane * 4) = p;
        if (lane == 0) { rmx[b * Nc + gi] = rm; rsm[b * Nc + gi] = rs; }
    }
}

// ---------------------------------------------------------------------------
extern "C" void kernel_launch(void* const* d_in, const int* in_sizes, int n_in,
                              void* d_out, int out_size, void* d_ws, size_t ws_size,
                              hipStream_t stream) {
    const float* adj     = (const float*)d_in[0];
    const float* feature = (const float*)d_in[1];
    const float* W0      = (const float*)d_in[2];
    const float* b0      = (const float*)d_in[3];
    const float* W1      = (const float*)d_in[4];
    const float* b1      = (const float*)d_in[5];
    const float* A1      = (const float*)d_in[6];
    const float* ab1     = (const float*)d_in[7];
    const float* A2      = (const float*)d_in[8];
    const float* ab2     = (const float*)d_in[9];

    char* ws = (char*)d_ws;
    float*  x1    = (float*)(ws);                  // 4096x320      5,242,880
    float*  sisj  = (float*)(ws + 5242880);        // 4096x128      2,097,152
    float*  P     = (float*)(ws + 7340032);        // 16x256x256    4,194,304
    float*  rmx   = (float*)(ws + 11534336);       //               16,384
    float*  rsm   = (float*)(ws + 11550720);       //               16,384
    float*  bias0 = (float*)(ws + 11567104);       //               1,792
    float*  bias1 = (float*)(ws + 11568896);       //               1,792
    ushort* F0h   = (ushort*)(ws + 11570688);      // 96x448x8      688,128
    ushort* F0l   = (ushort*)(ws + 12258816);      //               688,128
    ushort* F1h   = (ushort*)(ws + 12946944);      // 40x448x8      286,720
    ushort* F1l   = (ushort*)(ws + 13233664);      //               286,720
    ushort* Hh    = (ushort*)(ws + 13520384);      // 16x[32][320][8] 2,621,440
    ushort* Hl    = (ushort*)(ws + 16141824);      //               2,621,440
    float* outp   = (float*)d_out;

    convert_all<<<310, 256, 0, stream>>>(W0, b0, W1, b1, A1, ab1,
                                         F0h, F0l, F1h, F1l, bias0, bias1);

    for (int L = 0; L < 2; L++) {
        const float* X = L ? x1 : feature;
        const ushort* Fh = L ? F1h : F0h;
        const ushort* Fl = L ? F1l : F0l;
        const float* bf = L ? bias1 : bias0;
        int Kp = L ? 320 : 768;
        int AS = L ? 320 : 768;

        // [ h(split-only) | si | sj ] = X @ F + bias   (448 cols)
        mfma_gemm<<<dim3(7, 64, 1), 256, 0, stream>>>(
            X, 0, AS, Kp, Fh, Fl, 0, 448, bf,
            nullptr, 0, 0, 0, nullptr, nullptr, Hh, Hl, sisj);
        scores_kernel<<<dim3(16, 32), 256, 0, stream>>>(
            sisj, adj, A2, ab2, P, rmx, rsm);
        // out_rows = softmax_scale * (P @ H)   (merge fused in prologue)
        if (L == 0)
            mfma_gemm<<<dim3(5, 4, 16), 256, 0, stream>>>(
                P, 65536, 256, 256, Hh, Hl, 81920, 320, nullptr,
                x1, 81920, 320, 320, rmx, rsm, nullptr, nullptr, nullptr);
        else
            mfma_gemm<<<dim3(5, 4, 16), 256, 0, stream>>>(
                P, 65536, 256, 256, Hh, Hl, 81920, 320, nullptr,
                outp, 76800, 300, 300, rmx, rsm, nullptr, nullptr, nullptr);
    }
}